// Round 6
// baseline (135.728 us; speedup 1.0000x reference)
//
#include <hip/hip_runtime.h>
#include <hip/hip_bf16.h>
#include <hip/hip_fp16.h>

#define N_BCH 8
#define N_ATM 10000
#define N_ELM 100
#define N_ATOMS_TOT 80000
#define NBLK 1024
#define NTHR 512

typedef int   i4 __attribute__((ext_vector_type(4)));
typedef float f4 __attribute__((ext_vector_type(4)));

// Pre-pass: pack elm int32 -> u8 table in ws (80000 B). Cheap (0.3 MB read),
// and lets every edge block stage 80 KB instead of 320 KB (L2 burst / 4).
__launch_bounds__(256)
__global__ void pack_elm_kernel(const int* __restrict__ elm,
                                unsigned int* __restrict__ elm_u8) {
    int t = blockIdx.x * blockDim.x + threadIdx.x;
    if (t < N_ATOMS_TOT / 4) {
        i4 v = *(const i4*)(elm + 4 * t);
        elm_u8[t] = (unsigned int)(v[0] & 0xff)
                  | ((unsigned int)(v[1] & 0xff) << 8)
                  | ((unsigned int)(v[2] & 0xff) << 16)
                  | ((unsigned int)(v[3] & 0xff) << 24);
    }
}

// 512 thr, 4 waves/EU bound -> 128 VGPR budget (no spill with 2 load sets in
// flight). 80.5 KB LDS -> 2 blocks/CU resident, 1024 blocks = 4/CU uniform.
__launch_bounds__(NTHR, 4)
__global__ void edge_kernel(const unsigned int* __restrict__ elm_u8,
                            const float* __restrict__ kparam,
                            const float* __restrict__ radius,
                            const int* __restrict__ edge_n,
                            const int* __restrict__ edge_i,
                            const int* __restrict__ edge_j,
                            const float* __restrict__ sod,
                            float* __restrict__ out,
                            int nE) {
    __shared__ unsigned int s_elm32[N_ATOMS_TOT / 4];  // 80000 B u8 elm table
    __shared__ __half2 s_kr[128];                      // (k,r) half2
    __shared__ float s_red[8][N_BCH];

    const int nvec  = nE >> 2;
    const int chunk = (nvec + NBLK - 1) / NBLK;        // 1250
    const int base  = blockIdx.x * chunk;
    const int vmax  = min(base + chunk, nvec);

    const i4* en4 = (const i4*)edge_n;
    const i4* ei4 = (const i4*)edge_i;
    const i4* ej4 = (const i4*)edge_j;
    const f4* s4  = (const f4*)sod;

    // ---- prefetch sweep 0 BEFORE staging so the first memory round-trip
    //      overlaps the LDS staging phase ----
    int  start = base;                 // uniform sweep start
    int  v     = base + (int)threadIdx.x;
    bool p     = v < vmax;
    int  vc    = min(v, nvec - 1);
    i4 nn = __builtin_nontemporal_load(en4 + vc);
    i4 ii = __builtin_nontemporal_load(ei4 + vc);
    i4 jj = __builtin_nontemporal_load(ej4 + vc);
    f4 ss = __builtin_nontemporal_load(s4  + vc);

    // ---- stage elm u8 table (5000 x 16B) + kr half2 table ----
    {
        const i4* src = (const i4*)elm_u8;
        i4* dst = (i4*)s_elm32;
        for (int t = threadIdx.x; t < N_ATOMS_TOT / 16; t += NTHR)
            dst[t] = src[t];
        if (threadIdx.x < N_ELM)
            s_kr[threadIdx.x] =
                __floats2half2_rn(kparam[threadIdx.x], radius[threadIdx.x]);
    }
    __syncthreads();

    const unsigned char* s_elm = (const unsigned char*)s_elm32;

    float acc[N_BCH];
#pragma unroll
    for (int b = 0; b < N_BCH; ++b) acc[b] = 0.0f;

    if (base < vmax) {
        while (true) {
            // prefetch next sweep (wave-uniform condition)
            const int  nstart = start + NTHR;
            const bool more   = nstart < vmax;
            i4 nn2, ii2, jj2; f4 ss2;
            if (more) {
                int vc2 = min(v + NTHR, nvec - 1);
                nn2 = __builtin_nontemporal_load(en4 + vc2);
                ii2 = __builtin_nontemporal_load(ei4 + vc2);
                jj2 = __builtin_nontemporal_load(ej4 + vc2);
                ss2 = __builtin_nontemporal_load(s4  + vc2);
            }

            // lane mask folded into sod: 1e30 -> d>0 -> fmin -> val=0
            f4 ssm;
#pragma unroll
            for (int u = 0; u < 4; ++u) ssm[u] = p ? ss[u] : 1e30f;

#pragma unroll
            for (int u = 0; u < 4; ++u) {
                int n  = nn[u] & 7;
                int bb = n * N_ATM;
                int e_i = s_elm[bb + ii[u]];
                int e_j = s_elm[bb + jj[u]];
                __half2 krsum = __hadd2(s_kr[e_i], s_kr[e_j]);
                float kk = __low2float(krsum);
                float R  = __high2float(krsum);
                float dis = sqrtf(ssm[u]);
                float d   = fminf(dis - R, 0.0f);   // ==0 unless dis<R
                float val = kk * d * d;
#pragma unroll
                for (int b = 0; b < N_BCH; ++b)
                    acc[b] += (n == b) ? val : 0.0f;
            }

            if (!more) break;
            start = nstart;
            v += NTHR;
            p = v < vmax;
            nn = nn2; ii = ii2; jj = jj2; ss = ss2;
        }
    }

    // scalar tail (nE % 4)
    const int tail_start = nvec << 2;
    const int tail_n = nE - tail_start;
    const int gtid = blockIdx.x * NTHR + threadIdx.x;
    if (gtid < tail_n) {
        int e = tail_start + gtid;
        int n = edge_n[e] & 7;
        int e_i = s_elm[n * N_ATM + edge_i[e]];
        int e_j = s_elm[n * N_ATM + edge_j[e]];
        __half2 krsum = __hadd2(s_kr[e_i], s_kr[e_j]);
        float kk = __low2float(krsum);
        float R  = __high2float(krsum);
        float dis = sqrtf(sod[e]);
        float d   = fminf(dis - R, 0.0f);
        float val = kk * d * d;
#pragma unroll
        for (int b = 0; b < N_BCH; ++b)
            acc[b] += (n == b) ? val : 0.0f;
    }

    // ---- two-phase wave reduction ----
    const int lane = threadIdx.x & 63;
    const int wave = threadIdx.x >> 6;   // 8 waves
#pragma unroll
    for (int off = 8; off <= 32; off <<= 1) {
#pragma unroll
        for (int b = 0; b < N_BCH; ++b)
            acc[b] += __shfl_xor(acc[b], off, 64);
    }
    const int j = lane >> 3;
    float x = acc[0];
#pragma unroll
    for (int b = 1; b < N_BCH; ++b) x = (j == b) ? acc[b] : x;
#pragma unroll
    for (int off = 1; off <= 4; off <<= 1)
        x += __shfl_xor(x, off, 64);

    if ((lane & 7) == 0) s_red[wave][j] = x;
    __syncthreads();
    if (threadIdx.x < N_BCH) {
        float t = 0.0f;
#pragma unroll
        for (int w = 0; w < 8; ++w) t += s_red[w][threadIdx.x];
        atomicAdd(&out[threadIdx.x], t);
    }
}

extern "C" void kernel_launch(void* const* d_in, const int* in_sizes, int n_in,
                              void* d_out, int out_size, void* d_ws, size_t ws_size,
                              hipStream_t stream) {
    const int*   elm    = (const int*)d_in[0];
    const int*   edge_n = (const int*)d_in[1];
    const int*   edge_i = (const int*)d_in[2];
    const int*   edge_j = (const int*)d_in[3];
    const float* sod    = (const float*)d_in[4];
    const float* kparam = (const float*)d_in[5];
    const float* radius = (const float*)d_in[6];
    float* out = (float*)d_out;
    const int nE = in_sizes[1];

    unsigned int* elm_u8 = (unsigned int*)d_ws;  // 80000 B packed u8 table

    hipMemsetAsync(out, 0, out_size * sizeof(float), stream);
    hipLaunchKernelGGL(pack_elm_kernel, dim3((N_ATOMS_TOT / 4 + 255) / 256),
                       dim3(256), 0, stream, elm, elm_u8);
    hipLaunchKernelGGL(edge_kernel, dim3(NBLK), dim3(NTHR), 0, stream,
                       elm_u8, kparam, radius, edge_n, edge_i, edge_j, sod,
                       out, nE);
}

// Round 7
// 118.072 us; speedup vs baseline: 1.1495x; 1.1495x over previous
//
#include <hip/hip_runtime.h>
#include <hip/hip_bf16.h>
#include <hip/hip_fp16.h>

#define N_BCH 8
#define N_ATM 10000
#define N_ELM 100
#define N_ATOMS_TOT 80000

typedef int   i4 __attribute__((ext_vector_type(4)));
typedef float f4 __attribute__((ext_vector_type(4)));

// Pre-pass: pack elm (int32, values <100) into u8 table in ws (80000 B).
__launch_bounds__(256)
__global__ void pack_elm_kernel(const int* __restrict__ elm,
                                unsigned int* __restrict__ elm_u8) {
    int t = blockIdx.x * blockDim.x + threadIdx.x;
    if (t < N_ATOMS_TOT / 4) {
        i4 v = *(const i4*)(elm + 4 * t);
        elm_u8[t] = (unsigned int)(v[0] & 0xff)
                  | ((unsigned int)(v[1] & 0xff) << 8)
                  | ((unsigned int)(v[2] & 0xff) << 16)
                  | ((unsigned int)(v[3] & 0xff) << 24);
    }
}

// R4 champion structure: all divergent accesses in LDS, grid-stride main loop.
//   s_elm32 : 80000 B u8 element types (whole batch)
//   s_kr    : 100x half2(k,r) -> one ds_read_b32 per endpoint
// LDS ~79.1 KiB -> 2 blocks/CU x 1024 thr = 32 waves/CU.
__launch_bounds__(1024, 8)
__global__ void edge_kernel(const unsigned int* __restrict__ elm_u8,
                            const float* __restrict__ kparam,
                            const float* __restrict__ radius,
                            const int* __restrict__ edge_n,
                            const int* __restrict__ edge_i,
                            const int* __restrict__ edge_j,
                            const float* __restrict__ sod,
                            float* __restrict__ out,
                            int nE) {
    __shared__ unsigned int s_elm32[N_ATOMS_TOT / 4];  // 80000 B
    __shared__ __half2 s_kr[128];                      // 512 B (100 used)
    __shared__ float s_red[16][N_BCH];                 // 512 B

    // ---- stage elm table (int4-vectorized: 5000 x 16B) + kr half2 table ----
    {
        const i4* src = (const i4*)elm_u8;
        i4* dst = (i4*)s_elm32;
        for (int t = threadIdx.x; t < N_ATOMS_TOT / 16; t += 1024)
            dst[t] = src[t];
        if (threadIdx.x < N_ELM)
            s_kr[threadIdx.x] =
                __floats2half2_rn(kparam[threadIdx.x], radius[threadIdx.x]);
    }
    __syncthreads();

    const unsigned char* s_elm = (const unsigned char*)s_elm32;

    float acc[N_BCH];
#pragma unroll
    for (int b = 0; b < N_BCH; ++b) acc[b] = 0.0f;

    const int tid    = blockIdx.x * blockDim.x + threadIdx.x;
    const int stride = gridDim.x * blockDim.x;
    const int nvec   = nE >> 2;

    const i4* en4 = (const i4*)edge_n;
    const i4* ei4 = (const i4*)edge_i;
    const i4* ej4 = (const i4*)edge_j;
    const f4* s4  = (const f4*)sod;

    for (int v = tid; v < nvec; v += stride) {
        i4 nn = en4[v];         // plain loads: let L3-resident input serve hits
        i4 ii = ei4[v];
        i4 jj = ej4[v];
        f4 ss = s4[v];

#pragma unroll
        for (int u = 0; u < 4; ++u) {
            int n = nn[u];
            int base = n * N_ATM;
            int e_i = s_elm[base + ii[u]];
            int e_j = s_elm[base + jj[u]];
            __half2 krsum = __hadd2(s_kr[e_i], s_kr[e_j]);
            float kk = __low2float(krsum);
            float R  = __high2float(krsum);
            float dis = sqrtf(ss[u]);
            float d   = fminf(dis - R, 0.0f);   // ==0 unless dis<R (exact)
            float val = kk * d * d;
#pragma unroll
            for (int b = 0; b < N_BCH; ++b)
                acc[b] += (n == b) ? val : 0.0f;
        }
    }

    // scalar tail (nE % 4)
    const int tail_start = nvec << 2;
    const int tail_n = nE - tail_start;
    if (tid < tail_n) {
        int e = tail_start + tid;
        int n = edge_n[e];
        int e_i = s_elm[n * N_ATM + edge_i[e]];
        int e_j = s_elm[n * N_ATM + edge_j[e]];
        __half2 krsum = __hadd2(s_kr[e_i], s_kr[e_j]);
        float kk = __low2float(krsum);
        float R  = __high2float(krsum);
        float dis = sqrtf(sod[e]);
        float d   = fminf(dis - R, 0.0f);
        float val = kk * d * d;
#pragma unroll
        for (int b = 0; b < N_BCH; ++b)
            acc[b] += (n == b) ? val : 0.0f;
    }

    // ---- two-phase wave reduction ----
    const int lane = threadIdx.x & 63;
    const int wave = threadIdx.x >> 6;   // 16 waves
#pragma unroll
    for (int off = 8; off <= 32; off <<= 1) {
#pragma unroll
        for (int b = 0; b < N_BCH; ++b)
            acc[b] += __shfl_xor(acc[b], off, 64);
    }
    const int j = lane >> 3;
    float x = acc[0];
#pragma unroll
    for (int b = 1; b < N_BCH; ++b) x = (j == b) ? acc[b] : x;
#pragma unroll
    for (int off = 1; off <= 4; off <<= 1)
        x += __shfl_xor(x, off, 64);

    if ((lane & 7) == 0) s_red[wave][j] = x;
    __syncthreads();
    if (threadIdx.x < N_BCH) {
        float t = 0.0f;
#pragma unroll
        for (int w = 0; w < 16; ++w) t += s_red[w][threadIdx.x];
        atomicAdd(&out[threadIdx.x], t);
    }
}

extern "C" void kernel_launch(void* const* d_in, const int* in_sizes, int n_in,
                              void* d_out, int out_size, void* d_ws, size_t ws_size,
                              hipStream_t stream) {
    const int*   elm    = (const int*)d_in[0];
    const int*   edge_n = (const int*)d_in[1];
    const int*   edge_i = (const int*)d_in[2];
    const int*   edge_j = (const int*)d_in[3];
    const float* sod    = (const float*)d_in[4];
    const float* kparam = (const float*)d_in[5];
    const float* radius = (const float*)d_in[6];
    float* out = (float*)d_out;
    const int nE = in_sizes[1];

    unsigned int* elm_u8 = (unsigned int*)d_ws;  // 80000 B packed u8 table

    hipMemsetAsync(out, 0, out_size * sizeof(float), stream);
    hipLaunchKernelGGL(pack_elm_kernel, dim3((N_ATOMS_TOT / 4 + 255) / 256),
                       dim3(256), 0, stream, elm, elm_u8);
    // 512 blocks x 1024 thr: 2 blocks/CU resident, 32 waves/CU (R4 champion)
    hipLaunchKernelGGL(edge_kernel, dim3(512), dim3(1024), 0, stream,
                       elm_u8, kparam, radius, edge_n, edge_i, edge_j, sod,
                       out, nE);
}